// Round 1
// baseline (2257.238 us; speedup 1.0000x reference)
//
#include <hip/hip_runtime.h>

// Problem constants (match reference)
#define N_NODES 100000
#define N_EDGES 1200000
#define DIM     64
#define BGRAPHS 1000
#define NCLASS  10
#define BN_EPS  1e-5f

// ---------------------------------------------------------------------------
// Kernel 1: h0 = x (copy), x_struct = 0
// ---------------------------------------------------------------------------
__global__ void init_kernel(const float* __restrict__ x,
                            float* __restrict__ h0,
                            float* __restrict__ xs) {
    int idx = blockIdx.x * blockDim.x + threadIdx.x;
    const int n4 = N_NODES * DIM / 4;      // 1,600,000 float4
    if (idx < n4) {
        ((float4*)h0)[idx] = ((const float4*)x)[idx];
    }
    const int s4 = BGRAPHS * DIM / 4;      // 16,000 float4
    if (idx < s4) {
        ((float4*)xs)[idx] = make_float4(0.f, 0.f, 0.f, 0.f);
    }
}

// ---------------------------------------------------------------------------
// Kernel 2/4: scatter-add aggregation: out[dst[e]] += feat[src[e]]
// 16 threads per edge, each handles 4 contiguous floats (float4 gather).
// ---------------------------------------------------------------------------
__global__ void agg_kernel(const float* __restrict__ feat,
                           float* __restrict__ out,
                           const int* __restrict__ ei) {
    long long tid = (long long)blockIdx.x * blockDim.x + threadIdx.x;
    int e = (int)(tid >> 4);
    int q = (int)(tid & 15);
    if (e >= N_EDGES) return;
    int s = ei[e];
    int d = ei[N_EDGES + e];
    float4 v = ((const float4*)(feat + (long long)s * DIM))[q];
    float* p = out + (long long)d * DIM + q * 4;
    unsafeAtomicAdd(p + 0, v.x);
    unsafeAtomicAdd(p + 1, v.y);
    unsafeAtomicAdd(p + 2, v.z);
    unsafeAtomicAdd(p + 3, v.w);
}

// ---------------------------------------------------------------------------
// Kernel 3: fused conv1 MLP:
//   h1 = relu(bn1(h0 @ W1a + b1a)); h2 = relu(h1 @ W1b + b1b)
// writes h2 to BOTH bufB (gather source for agg2) and bufA (scatter init).
// Block: 256 threads, 32 rows. Wave = one rq (4 waves), col = lane -> all
// lanes of a wave read the same LDS h element (broadcast) and consecutive
// weight cols (2-way bank alias = free).
// ---------------------------------------------------------------------------
__global__ __launch_bounds__(256) void mlp1_kernel(
    const float* __restrict__ h0,
    const float* __restrict__ W1a, const float* __restrict__ b1a,
    const float* __restrict__ g1,  const float* __restrict__ be1,
    const float* __restrict__ m1,  const float* __restrict__ v1,
    const float* __restrict__ W1b, const float* __restrict__ b1b,
    float* __restrict__ h2, float* __restrict__ h3init) {
    __shared__ float wa[64 * 64];
    __shared__ float wb[64 * 64];
    __shared__ float ht[32 * 64];     // h0 tile, then h1 tile
    __shared__ float sc1[64], sh1[64];

    int t = threadIdx.x;
    int col = t & 63;
    int rq = t >> 6;

    for (int i = t; i < 4096; i += 256) { wa[i] = W1a[i]; wb[i] = W1b[i]; }
    if (t < 64) {
        float s = g1[t] / sqrtf(v1[t] + BN_EPS);
        sc1[t] = s;
        sh1[t] = be1[t] - m1[t] * s;
    }
    long long row0 = (long long)blockIdx.x * 32;
    for (int i = t; i < 512; i += 256) {      // 32 rows x 16 float4
        long long gr = row0 + (i >> 4);
        float4 v = (gr < N_NODES) ? ((const float4*)h0)[(gr << 4) + (i & 15)]
                                  : make_float4(0.f, 0.f, 0.f, 0.f);
        ((float4*)ht)[i] = v;
    }
    __syncthreads();

    float bias1 = b1a[col];
    float bias2 = b1b[col];
    float scl = sc1[col], shf = sh1[col];

    float h1v[8];
    #pragma unroll
    for (int j = 0; j < 8; ++j) {
        int r = rq + j * 4;
        float acc = 0.f;
        #pragma unroll
        for (int k = 0; k < 64; ++k) acc += ht[r * 64 + k] * wa[k * 64 + col];
        float val = (acc + bias1) * scl + shf;
        h1v[j] = fmaxf(val, 0.f);
    }
    __syncthreads();
    #pragma unroll
    for (int j = 0; j < 8; ++j) ht[(rq + j * 4) * 64 + col] = h1v[j];
    __syncthreads();
    #pragma unroll
    for (int j = 0; j < 8; ++j) {
        int r = rq + j * 4;
        long long gr = row0 + r;
        if (gr >= N_NODES) continue;
        float acc = 0.f;
        #pragma unroll
        for (int k = 0; k < 64; ++k) acc += ht[r * 64 + k] * wb[k * 64 + col];
        float v2 = fmaxf(acc + bias2, 0.f);
        h2[gr * 64 + col] = v2;
        h3init[gr * 64 + col] = v2;   // safe: this block's bufA rows already in LDS
    }
}

// ---------------------------------------------------------------------------
// Kernel 5: h4 = relu(bn2(h3 @ W2 + b2)); x_struct[batch[row]] += h4
// batch is sorted -> run-length accumulate per thread before atomics.
// ---------------------------------------------------------------------------
__global__ __launch_bounds__(256) void mlp2_kernel(
    const float* __restrict__ h3,
    const float* __restrict__ W2, const float* __restrict__ b2,
    const float* __restrict__ g2, const float* __restrict__ be2,
    const float* __restrict__ m2, const float* __restrict__ v2,
    const int* __restrict__ batch,
    float* __restrict__ xs) {
    __shared__ float w[64 * 64];
    __shared__ float ht[32 * 64];
    __shared__ float sc[64], sh[64];
    __shared__ int bt_s[32];

    int t = threadIdx.x;
    int col = t & 63;
    int rq = t >> 6;

    for (int i = t; i < 4096; i += 256) w[i] = W2[i];
    if (t < 64) {
        float s = g2[t] / sqrtf(v2[t] + BN_EPS);
        sc[t] = s;
        sh[t] = be2[t] - m2[t] * s;
    }
    long long row0 = (long long)blockIdx.x * 32;
    if (t < 32) {
        long long gr = row0 + t;
        bt_s[t] = (gr < N_NODES) ? batch[gr] : 0;
    }
    for (int i = t; i < 512; i += 256) {
        long long gr = row0 + (i >> 4);
        float4 v = (gr < N_NODES) ? ((const float4*)h3)[(gr << 4) + (i & 15)]
                                  : make_float4(0.f, 0.f, 0.f, 0.f);
        ((float4*)ht)[i] = v;
    }
    __syncthreads();

    float bias = b2[col];
    float scl = sc[col], shf = sh[col];

    int curb = -1;
    float curs = 0.f;
    #pragma unroll
    for (int j = 0; j < 8; ++j) {
        int r = rq + j * 4;
        long long gr = row0 + r;
        if (gr >= N_NODES) continue;
        float acc = 0.f;
        #pragma unroll
        for (int k = 0; k < 64; ++k) acc += ht[r * 64 + k] * w[k * 64 + col];
        float val = fmaxf((acc + bias) * scl + shf, 0.f);
        int bb = bt_s[r];
        if (bb != curb) {
            if (curb >= 0) unsafeAtomicAdd(&xs[curb * 64 + col], curs);
            curb = bb;
            curs = 0.f;
        }
        curs += val;
    }
    if (curb >= 0) unsafeAtomicAdd(&xs[curb * 64 + col], curs);
}

// ---------------------------------------------------------------------------
// Kernel 6: per-graph head: x_topo = relu(topo @ Wt + bt);
//           out = [x_struct, x_topo] @ Wc + bc
// One wave (64 threads) per graph.
// ---------------------------------------------------------------------------
__global__ __launch_bounds__(64) void head_kernel(
    const float* __restrict__ xs, const float* __restrict__ topo,
    const float* __restrict__ Wt, const float* __restrict__ bt,
    const float* __restrict__ Wc, const float* __restrict__ bc,
    float* __restrict__ out) {
    __shared__ float trow[64];
    __shared__ float comb[128];
    int b = blockIdx.x;
    int h = threadIdx.x;
    trow[h] = topo[b * 64 + h];
    __syncthreads();
    float acc = bt[h];
    #pragma unroll
    for (int k = 0; k < 64; ++k) acc += trow[k] * Wt[k * 64 + h];
    comb[h] = xs[b * 64 + h];
    comb[64 + h] = fmaxf(acc, 0.f);
    __syncthreads();
    if (h < NCLASS) {
        float o = bc[h];
        #pragma unroll
        for (int k = 0; k < 128; ++k) o += comb[k] * Wc[k * NCLASS + h];
        out[b * NCLASS + h] = o;
    }
}

// ---------------------------------------------------------------------------
extern "C" void kernel_launch(void* const* d_in, const int* in_sizes, int n_in,
                              void* d_out, int out_size, void* d_ws, size_t ws_size,
                              hipStream_t stream) {
    const float* x     = (const float*)d_in[0];
    const int*   ei    = (const int*)d_in[1];
    const int*   batch = (const int*)d_in[2];
    const float* topo  = (const float*)d_in[3];
    const float* W1a   = (const float*)d_in[4];
    const float* b1a   = (const float*)d_in[5];
    const float* g1    = (const float*)d_in[6];
    const float* be1   = (const float*)d_in[7];
    const float* m1    = (const float*)d_in[8];
    const float* v1    = (const float*)d_in[9];
    const float* W1b   = (const float*)d_in[10];
    const float* b1b   = (const float*)d_in[11];
    const float* W2    = (const float*)d_in[12];
    const float* b2    = (const float*)d_in[13];
    const float* g2    = (const float*)d_in[14];
    const float* be2   = (const float*)d_in[15];
    const float* m2    = (const float*)d_in[16];
    const float* v2    = (const float*)d_in[17];
    const float* Wt    = (const float*)d_in[18];
    const float* bt    = (const float*)d_in[19];
    const float* Wc    = (const float*)d_in[20];
    const float* bc    = (const float*)d_in[21];
    float* out = (float*)d_out;

    // Workspace layout (floats): bufA = h0/h3 (aliased), bufB = h2, xs = pool
    float* bufA = (float*)d_ws;
    float* bufB = bufA + (size_t)N_NODES * DIM;
    float* xs   = bufB + (size_t)N_NODES * DIM;

    const int n4 = N_NODES * DIM / 4;
    init_kernel<<<(n4 + 255) / 256, 256, 0, stream>>>(x, bufA, xs);

    const int agg_blocks = (int)(((long long)N_EDGES * 16 + 255) / 256);
    agg_kernel<<<agg_blocks, 256, 0, stream>>>(x, bufA, ei);      // h0 = x + scatter(x)

    mlp1_kernel<<<(N_NODES + 31) / 32, 256, 0, stream>>>(
        bufA, W1a, b1a, g1, be1, m1, v1, W1b, b1b, bufB, bufA);   // bufB=h2, bufA=h3 init

    agg_kernel<<<agg_blocks, 256, 0, stream>>>(bufB, bufA, ei);   // h3 = h2 + scatter(h2)

    mlp2_kernel<<<(N_NODES + 31) / 32, 256, 0, stream>>>(
        bufA, W2, b2, g2, be2, m2, v2, batch, xs);                // xs = pooled

    head_kernel<<<BGRAPHS, 64, 0, stream>>>(xs, topo, Wt, bt, Wc, bc, out);
}

// Round 2
// 455.057 us; speedup vs baseline: 4.9603x; 4.9603x over previous
//
#include <hip/hip_runtime.h>

// Problem constants (match reference)
#define N_NODES 100000
#define N_EDGES 1200000
#define DIM     64
#define BGRAPHS 1000
#define NCLASS  10
#define BN_EPS  1e-5f

// ---------------------------------------------------------------------------
// Kernel: zero deg[] and xs[]
// ---------------------------------------------------------------------------
__global__ void zero_kernel(int* __restrict__ deg, float* __restrict__ xs) {
    int i = blockIdx.x * blockDim.x + threadIdx.x;
    if (i < N_NODES) deg[i] = 0;
    if (i < BGRAPHS * DIM) xs[i] = 0.f;
}

// ---------------------------------------------------------------------------
// CSR build step 1: degree histogram over dst
// ---------------------------------------------------------------------------
__global__ void hist_kernel(const int* __restrict__ ei, int* __restrict__ deg) {
    int e = blockIdx.x * blockDim.x + threadIdx.x;
    if (e < N_EDGES) atomicAdd(&deg[ei[N_EDGES + e]], 1);
}

// ---------------------------------------------------------------------------
// CSR build step 2a: per-block (1024-elem) exclusive scan of deg -> rowptr,
// block sums -> bsum
// ---------------------------------------------------------------------------
__global__ __launch_bounds__(256) void scan1_kernel(const int* __restrict__ deg,
                                                    int* __restrict__ rowptr,
                                                    int* __restrict__ bsum) {
    __shared__ int tmp[256];
    int t = threadIdx.x;
    int base = blockIdx.x * 1024;
    int v[4]; int s = 0;
    #pragma unroll
    for (int j = 0; j < 4; ++j) {
        int idx = base + t * 4 + j;
        v[j] = (idx < N_NODES) ? deg[idx] : 0;
        s += v[j];
    }
    tmp[t] = s;
    __syncthreads();
    for (int off = 1; off < 256; off <<= 1) {
        int a = (t >= off) ? tmp[t - off] : 0;
        __syncthreads();
        tmp[t] += a;
        __syncthreads();
    }
    int excl = tmp[t] - s;
    if (t == 255) bsum[blockIdx.x] = tmp[255];
    int run = excl;
    #pragma unroll
    for (int j = 0; j < 4; ++j) {
        int idx = base + t * 4 + j;
        if (idx < N_NODES) { rowptr[idx] = run; }
        run += v[j];
    }
}

// ---------------------------------------------------------------------------
// CSR build step 2b: single-block exclusive scan of the 98 block sums
// ---------------------------------------------------------------------------
__global__ __launch_bounds__(128) void scan2_kernel(int* __restrict__ bsum, int nb) {
    __shared__ int tmp[128];
    int t = threadIdx.x;
    int v = (t < nb) ? bsum[t] : 0;
    tmp[t] = v;
    __syncthreads();
    for (int off = 1; off < 128; off <<= 1) {
        int a = (t >= off) ? tmp[t - off] : 0;
        __syncthreads();
        tmp[t] += a;
        __syncthreads();
    }
    if (t < nb) bsum[t] = tmp[t] - v;
}

// ---------------------------------------------------------------------------
// CSR build step 2c: add block offsets; produce cursor copy; rowptr[N]=E
// ---------------------------------------------------------------------------
__global__ void scan3_kernel(int* __restrict__ rowptr, const int* __restrict__ bsum,
                             int* __restrict__ cursor) {
    int i = blockIdx.x * blockDim.x + threadIdx.x;
    if (i < N_NODES) {
        int v = rowptr[i] + bsum[i >> 10];
        rowptr[i] = v;
        cursor[i] = v;
    }
    if (i == 0) rowptr[N_NODES] = N_EDGES;
}

// ---------------------------------------------------------------------------
// CSR build step 3: bucket src ids into csr_src by dst
// ---------------------------------------------------------------------------
__global__ void fill_kernel(const int* __restrict__ ei, int* __restrict__ cursor,
                            int* __restrict__ csr_src) {
    int e = blockIdx.x * blockDim.x + threadIdx.x;
    if (e < N_EDGES) {
        int d = ei[N_EDGES + e];
        int pos = atomicAdd(&cursor[d], 1);
        csr_src[pos] = ei[e];
    }
}

// ---------------------------------------------------------------------------
// Gather aggregation: out[i] = feat[i] + sum_{s in nbrs(i)} feat[s]
// 16 lanes per node (float4 per lane), 16 nodes per 256-thread block.
// Software-pipelined neighbor index load.
// ---------------------------------------------------------------------------
__global__ __launch_bounds__(256) void gather_kernel(const float* __restrict__ feat,
                                                     const int* __restrict__ rowptr,
                                                     const int* __restrict__ csr_src,
                                                     float* __restrict__ out) {
    int g = blockIdx.x * 16 + (threadIdx.x >> 4);
    int q = threadIdx.x & 15;
    if (g >= N_NODES) return;
    const float4* f4 = (const float4*)feat;
    int beg = rowptr[g], end = rowptr[g + 1];
    float4 acc = f4[(long long)g * 16 + q];
    int k = beg;
    int sn = (k < end) ? csr_src[k] : 0;
    while (k < end) {
        int sc = sn;
        ++k;
        if (k < end) sn = csr_src[k];
        float4 v = f4[(long long)sc * 16 + q];
        acc.x += v.x; acc.y += v.y; acc.z += v.z; acc.w += v.w;
    }
    ((float4*)out)[(long long)g * 16 + q] = acc;
}

// ---------------------------------------------------------------------------
// Fused conv1 MLP: h1 = relu(bn1(h0 @ W1a + b1a)); h2 = relu(h1 @ W1b + b1b)
// ---------------------------------------------------------------------------
__global__ __launch_bounds__(256) void mlp1_kernel(
    const float* __restrict__ h0,
    const float* __restrict__ W1a, const float* __restrict__ b1a,
    const float* __restrict__ g1,  const float* __restrict__ be1,
    const float* __restrict__ m1,  const float* __restrict__ v1,
    const float* __restrict__ W1b, const float* __restrict__ b1b,
    float* __restrict__ h2) {
    __shared__ float wa[64 * 64];
    __shared__ float wb[64 * 64];
    __shared__ float ht[32 * 64];
    __shared__ float sc1[64], sh1[64];

    int t = threadIdx.x;
    int col = t & 63;
    int rq = t >> 6;

    for (int i = t; i < 4096; i += 256) { wa[i] = W1a[i]; wb[i] = W1b[i]; }
    if (t < 64) {
        float s = g1[t] / sqrtf(v1[t] + BN_EPS);
        sc1[t] = s;
        sh1[t] = be1[t] - m1[t] * s;
    }
    long long row0 = (long long)blockIdx.x * 32;
    for (int i = t; i < 512; i += 256) {
        long long gr = row0 + (i >> 4);
        float4 v = (gr < N_NODES) ? ((const float4*)h0)[(gr << 4) + (i & 15)]
                                  : make_float4(0.f, 0.f, 0.f, 0.f);
        ((float4*)ht)[i] = v;
    }
    __syncthreads();

    float bias1 = b1a[col];
    float bias2 = b1b[col];
    float scl = sc1[col], shf = sh1[col];

    float h1v[8];
    #pragma unroll
    for (int j = 0; j < 8; ++j) {
        int r = rq + j * 4;
        float acc = 0.f;
        #pragma unroll
        for (int k = 0; k < 64; ++k) acc += ht[r * 64 + k] * wa[k * 64 + col];
        h1v[j] = fmaxf((acc + bias1) * scl + shf, 0.f);
    }
    __syncthreads();
    #pragma unroll
    for (int j = 0; j < 8; ++j) ht[(rq + j * 4) * 64 + col] = h1v[j];
    __syncthreads();
    #pragma unroll
    for (int j = 0; j < 8; ++j) {
        int r = rq + j * 4;
        long long gr = row0 + r;
        if (gr >= N_NODES) continue;
        float acc = 0.f;
        #pragma unroll
        for (int k = 0; k < 64; ++k) acc += ht[r * 64 + k] * wb[k * 64 + col];
        h2[gr * 64 + col] = fmaxf(acc + bias2, 0.f);
    }
}

// ---------------------------------------------------------------------------
// conv2 + pool: h4 = relu(bn2(h3 @ W2 + b2)); x_struct[batch[row]] += h4
// batch sorted -> run-length accumulate before atomics.
// ---------------------------------------------------------------------------
__global__ __launch_bounds__(256) void mlp2_kernel(
    const float* __restrict__ h3,
    const float* __restrict__ W2, const float* __restrict__ b2,
    const float* __restrict__ g2, const float* __restrict__ be2,
    const float* __restrict__ m2, const float* __restrict__ v2,
    const int* __restrict__ batch,
    float* __restrict__ xs) {
    __shared__ float w[64 * 64];
    __shared__ float ht[32 * 64];
    __shared__ float sc[64], sh[64];
    __shared__ int bt_s[32];

    int t = threadIdx.x;
    int col = t & 63;
    int rq = t >> 6;

    for (int i = t; i < 4096; i += 256) w[i] = W2[i];
    if (t < 64) {
        float s = g2[t] / sqrtf(v2[t] + BN_EPS);
        sc[t] = s;
        sh[t] = be2[t] - m2[t] * s;
    }
    long long row0 = (long long)blockIdx.x * 32;
    if (t < 32) {
        long long gr = row0 + t;
        bt_s[t] = (gr < N_NODES) ? batch[gr] : 0;
    }
    for (int i = t; i < 512; i += 256) {
        long long gr = row0 + (i >> 4);
        float4 v = (gr < N_NODES) ? ((const float4*)h3)[(gr << 4) + (i & 15)]
                                  : make_float4(0.f, 0.f, 0.f, 0.f);
        ((float4*)ht)[i] = v;
    }
    __syncthreads();

    float bias = b2[col];
    float scl = sc[col], shf = sh[col];

    int curb = -1;
    float curs = 0.f;
    #pragma unroll
    for (int j = 0; j < 8; ++j) {
        int r = rq + j * 4;
        long long gr = row0 + r;
        if (gr >= N_NODES) continue;
        float acc = 0.f;
        #pragma unroll
        for (int k = 0; k < 64; ++k) acc += ht[r * 64 + k] * w[k * 64 + col];
        float val = fmaxf((acc + bias) * scl + shf, 0.f);
        int bb = bt_s[r];
        if (bb != curb) {
            if (curb >= 0) unsafeAtomicAdd(&xs[curb * 64 + col], curs);
            curb = bb;
            curs = 0.f;
        }
        curs += val;
    }
    if (curb >= 0) unsafeAtomicAdd(&xs[curb * 64 + col], curs);
}

// ---------------------------------------------------------------------------
// Head: x_topo = relu(topo @ Wt + bt); out = [x_struct, x_topo] @ Wc + bc
// ---------------------------------------------------------------------------
__global__ __launch_bounds__(64) void head_kernel(
    const float* __restrict__ xs, const float* __restrict__ topo,
    const float* __restrict__ Wt, const float* __restrict__ bt,
    const float* __restrict__ Wc, const float* __restrict__ bc,
    float* __restrict__ out) {
    __shared__ float trow[64];
    __shared__ float comb[128];
    int b = blockIdx.x;
    int h = threadIdx.x;
    trow[h] = topo[b * 64 + h];
    __syncthreads();
    float acc = bt[h];
    #pragma unroll
    for (int k = 0; k < 64; ++k) acc += trow[k] * Wt[k * 64 + h];
    comb[h] = xs[b * 64 + h];
    comb[64 + h] = fmaxf(acc, 0.f);
    __syncthreads();
    if (h < NCLASS) {
        float o = bc[h];
        #pragma unroll
        for (int k = 0; k < 128; ++k) o += comb[k] * Wc[k * NCLASS + h];
        out[b * NCLASS + h] = o;
    }
}

// ---------------------------------------------------------------------------
extern "C" void kernel_launch(void* const* d_in, const int* in_sizes, int n_in,
                              void* d_out, int out_size, void* d_ws, size_t ws_size,
                              hipStream_t stream) {
    const float* x     = (const float*)d_in[0];
    const int*   ei    = (const int*)d_in[1];
    const int*   batch = (const int*)d_in[2];
    const float* topo  = (const float*)d_in[3];
    const float* W1a   = (const float*)d_in[4];
    const float* b1a   = (const float*)d_in[5];
    const float* g1    = (const float*)d_in[6];
    const float* be1   = (const float*)d_in[7];
    const float* m1    = (const float*)d_in[8];
    const float* v1    = (const float*)d_in[9];
    const float* W1b   = (const float*)d_in[10];
    const float* b1b   = (const float*)d_in[11];
    const float* W2    = (const float*)d_in[12];
    const float* b2    = (const float*)d_in[13];
    const float* g2    = (const float*)d_in[14];
    const float* be2   = (const float*)d_in[15];
    const float* m2    = (const float*)d_in[16];
    const float* v2    = (const float*)d_in[17];
    const float* Wt    = (const float*)d_in[18];
    const float* bt    = (const float*)d_in[19];
    const float* Wc    = (const float*)d_in[20];
    const float* bc    = (const float*)d_in[21];
    float* out = (float*)d_out;

    // Workspace layout (16B-aligned chunks)
    char* p = (char*)d_ws;
    float* bufA    = (float*)p; p += (size_t)N_NODES * DIM * 4;       // 25.6 MB
    float* bufB    = (float*)p; p += (size_t)N_NODES * DIM * 4;       // 25.6 MB
    float* xs      = (float*)p; p += (size_t)BGRAPHS * DIM * 4;       // 256 KB
    int*   deg     = (int*)p;   p += (size_t)(N_NODES + 16) * 4;      // 400 KB
    int*   rowptr  = (int*)p;   p += (size_t)(N_NODES + 16) * 4;      // 400 KB
    int*   cursor  = (int*)p;   p += (size_t)(N_NODES + 16) * 4;      // 400 KB
    int*   bsum    = (int*)p;   p += 256 * 4;
    int*   csr_src = (int*)p;                                          // 4.8 MB

    const int NB_N   = (N_NODES + 255) / 256;       // 391
    const int NB_E   = (N_EDGES + 255) / 256;       // 4688
    const int NB_SC  = (N_NODES + 1023) / 1024;     // 98

    zero_kernel<<<NB_N, 256, 0, stream>>>(deg, xs);
    hist_kernel<<<NB_E, 256, 0, stream>>>(ei, deg);
    scan1_kernel<<<NB_SC, 256, 0, stream>>>(deg, rowptr, bsum);
    scan2_kernel<<<1, 128, 0, stream>>>(bsum, NB_SC);
    scan3_kernel<<<NB_N, 256, 0, stream>>>(rowptr, bsum, cursor);
    fill_kernel<<<NB_E, 256, 0, stream>>>(ei, cursor, csr_src);

    // agg1: bufA = x + scatter(x)
    gather_kernel<<<(N_NODES + 15) / 16, 256, 0, stream>>>(x, rowptr, csr_src, bufA);
    // conv1 MLP: bufB = h2
    mlp1_kernel<<<(N_NODES + 31) / 32, 256, 0, stream>>>(
        bufA, W1a, b1a, g1, be1, m1, v1, W1b, b1b, bufB);
    // agg2: bufA = h2 + scatter(h2)
    gather_kernel<<<(N_NODES + 15) / 16, 256, 0, stream>>>(bufB, rowptr, csr_src, bufA);
    // conv2 + pool
    mlp2_kernel<<<(N_NODES + 31) / 32, 256, 0, stream>>>(
        bufA, W2, b2, g2, be2, m2, v2, batch, xs);
    // head
    head_kernel<<<BGRAPHS, 64, 0, stream>>>(xs, topo, Wt, bt, Wc, bc, out);
}

// Round 3
// 334.895 us; speedup vs baseline: 6.7401x; 1.3588x over previous
//
#include <hip/hip_runtime.h>

// Problem constants (match reference)
#define N_NODES 100000
#define N_EDGES 1200000
#define DIM     64
#define BGRAPHS 1000
#define NCLASS  10
#define BN_EPS  1e-5f

typedef __attribute__((ext_vector_type(8))) short   bfx8;   // 8 bf16 (4 VGPRs) MFMA A/B frag
typedef __attribute__((ext_vector_type(4))) float   f32x4;  // MFMA C/D frag
typedef __attribute__((ext_vector_type(8))) unsigned short u16x8;

__device__ __forceinline__ unsigned short f2bf(float f) {
    unsigned u = __builtin_bit_cast(unsigned, f);
    unsigned r = (u + 0x7FFFu + ((u >> 16) & 1u)) >> 16;   // RNE
    return (unsigned short)r;
}
__device__ __forceinline__ float bf2f(unsigned short h) {
    unsigned u = ((unsigned)h) << 16;
    return __builtin_bit_cast(float, u);
}

// ---------------------------------------------------------------------------
// zero deg[] and xs[]
// ---------------------------------------------------------------------------
__global__ void zero_kernel(int* __restrict__ deg, float* __restrict__ xs) {
    int i = blockIdx.x * blockDim.x + threadIdx.x;
    if (i < N_NODES) deg[i] = 0;
    if (i < BGRAPHS * DIM) xs[i] = 0.f;
}

// ---------------------------------------------------------------------------
// fp32 -> bf16 convert (8 floats / thread)
// ---------------------------------------------------------------------------
__global__ void convert_kernel(const float* __restrict__ x, unsigned short* __restrict__ xb) {
    int i = blockIdx.x * blockDim.x + threadIdx.x;
    const int n8 = N_NODES * DIM / 8;
    if (i < n8) {
        float4 a = ((const float4*)x)[i * 2];
        float4 b = ((const float4*)x)[i * 2 + 1];
        u16x8 o;
        o[0] = f2bf(a.x); o[1] = f2bf(a.y); o[2] = f2bf(a.z); o[3] = f2bf(a.w);
        o[4] = f2bf(b.x); o[5] = f2bf(b.y); o[6] = f2bf(b.z); o[7] = f2bf(b.w);
        ((u16x8*)xb)[i] = o;
    }
}

// ---------------------------------------------------------------------------
// CSR build: degree histogram over dst
// ---------------------------------------------------------------------------
__global__ void hist_kernel(const int* __restrict__ ei, int* __restrict__ deg) {
    int e = blockIdx.x * blockDim.x + threadIdx.x;
    if (e < N_EDGES) atomicAdd(&deg[ei[N_EDGES + e]], 1);
}

// ---------------------------------------------------------------------------
// per-block (1024-elem) exclusive scan of deg -> rowptr, block sums -> bsum
// ---------------------------------------------------------------------------
__global__ __launch_bounds__(256) void scan1_kernel(const int* __restrict__ deg,
                                                    int* __restrict__ rowptr,
                                                    int* __restrict__ bsum) {
    __shared__ int tmp[256];
    int t = threadIdx.x;
    int base = blockIdx.x * 1024;
    int v[4]; int s = 0;
    #pragma unroll
    for (int j = 0; j < 4; ++j) {
        int idx = base + t * 4 + j;
        v[j] = (idx < N_NODES) ? deg[idx] : 0;
        s += v[j];
    }
    tmp[t] = s;
    __syncthreads();
    for (int off = 1; off < 256; off <<= 1) {
        int a = (t >= off) ? tmp[t - off] : 0;
        __syncthreads();
        tmp[t] += a;
        __syncthreads();
    }
    int excl = tmp[t] - s;
    if (t == 255) bsum[blockIdx.x] = tmp[255];
    int run = excl;
    #pragma unroll
    for (int j = 0; j < 4; ++j) {
        int idx = base + t * 4 + j;
        if (idx < N_NODES) rowptr[idx] = run;
        run += v[j];
    }
}

__global__ __launch_bounds__(128) void scan2_kernel(int* __restrict__ bsum, int nb) {
    __shared__ int tmp[128];
    int t = threadIdx.x;
    int v = (t < nb) ? bsum[t] : 0;
    tmp[t] = v;
    __syncthreads();
    for (int off = 1; off < 128; off <<= 1) {
        int a = (t >= off) ? tmp[t - off] : 0;
        __syncthreads();
        tmp[t] += a;
        __syncthreads();
    }
    if (t < nb) bsum[t] = tmp[t] - v;
}

__global__ void scan3_kernel(int* __restrict__ rowptr, const int* __restrict__ bsum,
                             int* __restrict__ cursor) {
    int i = blockIdx.x * blockDim.x + threadIdx.x;
    if (i < N_NODES) {
        int v = rowptr[i] + bsum[i >> 10];
        rowptr[i] = v;
        cursor[i] = v;
    }
    if (i == 0) rowptr[N_NODES] = N_EDGES;
}

__global__ void fill_kernel(const int* __restrict__ ei, int* __restrict__ cursor,
                            int* __restrict__ csr_src) {
    int e = blockIdx.x * blockDim.x + threadIdx.x;
    if (e < N_EDGES) {
        int d = ei[N_EDGES + e];
        int pos = atomicAdd(&cursor[d], 1);
        csr_src[pos] = ei[e];
    }
}

// ---------------------------------------------------------------------------
// bf16 gather aggregation: out[i] = feat[i] + sum_{s in nbrs(i)} feat[s]
// 8 lanes per node (16B = 8 bf16 per lane), 32 nodes per 256-thread block.
// fp32 accumulate, bf16 out.
// ---------------------------------------------------------------------------
__global__ __launch_bounds__(256) void gather_kernel(const unsigned short* __restrict__ feat,
                                                     const int* __restrict__ rowptr,
                                                     const int* __restrict__ csr_src,
                                                     unsigned short* __restrict__ out) {
    int t = threadIdx.x;
    int node = blockIdx.x * 32 + (t >> 3);
    int q = t & 7;
    if (node >= N_NODES) return;
    const u16x8* f8 = (const u16x8*)feat;
    u16x8 sv = f8[(long long)node * 8 + q];
    float acc[8];
    #pragma unroll
    for (int j = 0; j < 8; ++j) acc[j] = bf2f(sv[j]);
    int beg = rowptr[node], end = rowptr[node + 1];
    int k = beg;
    int sn = (k < end) ? csr_src[k] : 0;
    while (k < end) {
        int sc = sn;
        ++k;
        if (k < end) sn = csr_src[k];
        u16x8 v = f8[(long long)sc * 8 + q];
        #pragma unroll
        for (int j = 0; j < 8; ++j) acc[j] += bf2f(v[j]);
    }
    u16x8 o;
    #pragma unroll
    for (int j = 0; j < 8; ++j) o[j] = f2bf(acc[j]);
    ((u16x8*)out)[(long long)node * 8 + q] = o;
}

// ---------------------------------------------------------------------------
// B-fragment loader: element j = W[(kt*32 + q*8 + j)][col]  (fp32 W -> bf16)
// ---------------------------------------------------------------------------
__device__ __forceinline__ bfx8 load_wfrag(const float* __restrict__ W, int kt, int q, int col) {
    bfx8 f;
    #pragma unroll
    for (int j = 0; j < 8; ++j)
        f[j] = (short)f2bf(W[(kt * 32 + q * 8 + j) * 64 + col]);
    return f;
}

// ---------------------------------------------------------------------------
// MFMA conv1 MLP: h2 = relu(relu(bn1(h0 @ W1a + b1a)) @ W1b + b1b)
// Block = 4 waves; wave w computes rows blk*64 + w*16 .. +15 (16x64 tile).
// A-frags from global (bf16); weights as B-frags in registers; h1 transposed
// C-layout -> A-layout through a wave-private LDS tile.
// ---------------------------------------------------------------------------
__global__ __launch_bounds__(256) void mlp1_kernel(
    const unsigned short* __restrict__ h0,
    const float* __restrict__ W1a, const float* __restrict__ b1a,
    const float* __restrict__ g1,  const float* __restrict__ be1,
    const float* __restrict__ m1,  const float* __restrict__ v1,
    const float* __restrict__ W1b, const float* __restrict__ b1b,
    unsigned short* __restrict__ h2) {
    __shared__ unsigned short h1t[4][16 * 72];   // padded stride 72 (144B, 16B-aligned)
    __shared__ unsigned short outt[4][16 * 64];

    int t = threadIdx.x;
    int w = t >> 6, lane = t & 63;
    int m = lane & 15, q = lane >> 4;
    int row0 = blockIdx.x * 64 + w * 16;

    bfx8 wa[4][2], wb[4][2];
    #pragma unroll
    for (int nt = 0; nt < 4; ++nt) {
        #pragma unroll
        for (int kt = 0; kt < 2; ++kt) {
            wa[nt][kt] = load_wfrag(W1a, kt, q, nt * 16 + m);
            wb[nt][kt] = load_wfrag(W1b, kt, q, nt * 16 + m);
        }
    }
    float A1[4], B1[4], B2c[4];
    #pragma unroll
    for (int nt = 0; nt < 4; ++nt) {
        int c = nt * 16 + m;
        float s = g1[c] * rsqrtf(v1[c] + BN_EPS);
        A1[nt] = s;
        B1[nt] = b1a[c] * s + (be1[c] - m1[c] * s);
        B2c[nt] = b1b[c];
    }

    // layer 1
    int rowA = row0 + m;
    if (rowA > N_NODES - 1) rowA = N_NODES - 1;
    const bfx8* ap = (const bfx8*)(h0 + (long long)rowA * 64);
    bfx8 a0 = ap[q];        // k = 0*32 + q*8 + j
    bfx8 a1 = ap[4 + q];    // k = 32 + q*8 + j
    f32x4 acc[4];
    #pragma unroll
    for (int nt = 0; nt < 4; ++nt) {
        acc[nt] = (f32x4){0.f, 0.f, 0.f, 0.f};
        acc[nt] = __builtin_amdgcn_mfma_f32_16x16x32_bf16(a0, wa[nt][0], acc[nt], 0, 0, 0);
        acc[nt] = __builtin_amdgcn_mfma_f32_16x16x32_bf16(a1, wa[nt][1], acc[nt], 0, 0, 0);
    }
    // epilogue1: C layout (row = q*4+r, col = nt*16+m) -> LDS (bf16, stride 72)
    #pragma unroll
    for (int nt = 0; nt < 4; ++nt)
        #pragma unroll
        for (int r = 0; r < 4; ++r) {
            float v = fmaxf(acc[nt][r] * A1[nt] + B1[nt], 0.f);
            h1t[w][(q * 4 + r) * 72 + nt * 16 + m] = f2bf(v);
        }
    __syncthreads();

    // layer 2: A-frags from LDS
    const bfx8* hp = (const bfx8*)&h1t[w][m * 72];
    bfx8 c0 = hp[q];
    bfx8 c1 = hp[4 + q];
    f32x4 acc2[4];
    #pragma unroll
    for (int nt = 0; nt < 4; ++nt) {
        acc2[nt] = (f32x4){0.f, 0.f, 0.f, 0.f};
        acc2[nt] = __builtin_amdgcn_mfma_f32_16x16x32_bf16(c0, wb[nt][0], acc2[nt], 0, 0, 0);
        acc2[nt] = __builtin_amdgcn_mfma_f32_16x16x32_bf16(c1, wb[nt][1], acc2[nt], 0, 0, 0);
    }
    #pragma unroll
    for (int nt = 0; nt < 4; ++nt)
        #pragma unroll
        for (int r = 0; r < 4; ++r) {
            float v = fmaxf(acc2[nt][r] + B2c[nt], 0.f);
            outt[w][(q * 4 + r) * 64 + nt * 16 + m] = f2bf(v);
        }
    __syncthreads();

    // coalesced copy-out: 16 rows x 128B per wave
    #pragma unroll
    for (int i = lane; i < 128; i += 64) {
        int rr = i >> 3, cc = i & 7;
        int rg = row0 + rr;
        if (rg < N_NODES)
            ((float4*)h2)[(long long)rg * 8 + cc] = *(const float4*)&outt[w][rr * 64 + cc * 8];
    }
}

// ---------------------------------------------------------------------------
// MFMA conv2 + pool: h4 = relu(bn2(h3 @ W2 + b2)); xs[batch[row]] += h4
// ---------------------------------------------------------------------------
__global__ __launch_bounds__(256) void mlp2_kernel(
    const unsigned short* __restrict__ h3,
    const float* __restrict__ W2, const float* __restrict__ b2,
    const float* __restrict__ g2, const float* __restrict__ be2,
    const float* __restrict__ m2, const float* __restrict__ v2,
    const int* __restrict__ batch,
    float* __restrict__ xs) {
    __shared__ float pool[64 * 64];   // 16KB
    __shared__ int bts[64];

    int t = threadIdx.x;
    int w = t >> 6, lane = t & 63;
    int m = lane & 15, q = lane >> 4;
    int row0b = blockIdx.x * 64;
    int row0 = row0b + w * 16;

    bfx8 wf[4][2];
    #pragma unroll
    for (int nt = 0; nt < 4; ++nt)
        #pragma unroll
        for (int kt = 0; kt < 2; ++kt)
            wf[nt][kt] = load_wfrag(W2, kt, q, nt * 16 + m);
    float A[4], Bc[4];
    #pragma unroll
    for (int nt = 0; nt < 4; ++nt) {
        int c = nt * 16 + m;
        float s = g2[c] * rsqrtf(v2[c] + BN_EPS);
        A[nt] = s;
        Bc[nt] = b2[c] * s + (be2[c] - m2[c] * s);
    }
    if (t < 64) {
        int rg = row0b + t;
        bts[t] = (rg < N_NODES) ? batch[rg] : -1;
    }

    int rowA = row0 + m;
    if (rowA > N_NODES - 1) rowA = N_NODES - 1;
    const bfx8* ap = (const bfx8*)(h3 + (long long)rowA * 64);
    bfx8 a0 = ap[q];
    bfx8 a1 = ap[4 + q];
    f32x4 acc[4];
    #pragma unroll
    for (int nt = 0; nt < 4; ++nt) {
        acc[nt] = (f32x4){0.f, 0.f, 0.f, 0.f};
        acc[nt] = __builtin_amdgcn_mfma_f32_16x16x32_bf16(a0, wf[nt][0], acc[nt], 0, 0, 0);
        acc[nt] = __builtin_amdgcn_mfma_f32_16x16x32_bf16(a1, wf[nt][1], acc[nt], 0, 0, 0);
    }
    #pragma unroll
    for (int nt = 0; nt < 4; ++nt)
        #pragma unroll
        for (int r = 0; r < 4; ++r) {
            float v = fmaxf(acc[nt][r] * A[nt] + Bc[nt], 0.f);
            pool[(w * 16 + q * 4 + r) * 64 + nt * 16 + m] = v;
        }
    __syncthreads();

    // run-length pooled atomics (batch is sorted)
    int col = t & 63;
    int r0 = (t >> 6) * 16;
    int cb = bts[r0];
    float cur = 0.f;
    #pragma unroll
    for (int r = 0; r < 16; ++r) {
        int b = bts[r0 + r];
        if (b != cb) {
            if (cb >= 0) unsafeAtomicAdd(&xs[cb * 64 + col], cur);
            cb = b;
            cur = 0.f;
        }
        cur += pool[(r0 + r) * 64 + col];
    }
    if (cb >= 0) unsafeAtomicAdd(&xs[cb * 64 + col], cur);
}

// ---------------------------------------------------------------------------
// Head: x_topo = relu(topo @ Wt + bt); out = [x_struct, x_topo] @ Wc + bc
// ---------------------------------------------------------------------------
__global__ __launch_bounds__(64) void head_kernel(
    const float* __restrict__ xs, const float* __restrict__ topo,
    const float* __restrict__ Wt, const float* __restrict__ bt,
    const float* __restrict__ Wc, const float* __restrict__ bc,
    float* __restrict__ out) {
    __shared__ float trow[64];
    __shared__ float comb[128];
    int b = blockIdx.x;
    int h = threadIdx.x;
    trow[h] = topo[b * 64 + h];
    __syncthreads();
    float acc = bt[h];
    #pragma unroll
    for (int k = 0; k < 64; ++k) acc += trow[k] * Wt[k * 64 + h];
    comb[h] = xs[b * 64 + h];
    comb[64 + h] = fmaxf(acc, 0.f);
    __syncthreads();
    if (h < NCLASS) {
        float o = bc[h];
        #pragma unroll
        for (int k = 0; k < 128; ++k) o += comb[k] * Wc[k * NCLASS + h];
        out[b * NCLASS + h] = o;
    }
}

// ---------------------------------------------------------------------------
extern "C" void kernel_launch(void* const* d_in, const int* in_sizes, int n_in,
                              void* d_out, int out_size, void* d_ws, size_t ws_size,
                              hipStream_t stream) {
    const float* x     = (const float*)d_in[0];
    const int*   ei    = (const int*)d_in[1];
    const int*   batch = (const int*)d_in[2];
    const float* topo  = (const float*)d_in[3];
    const float* W1a   = (const float*)d_in[4];
    const float* b1a   = (const float*)d_in[5];
    const float* g1    = (const float*)d_in[6];
    const float* be1   = (const float*)d_in[7];
    const float* m1    = (const float*)d_in[8];
    const float* v1    = (const float*)d_in[9];
    const float* W1b   = (const float*)d_in[10];
    const float* b1b   = (const float*)d_in[11];
    const float* W2    = (const float*)d_in[12];
    const float* b2    = (const float*)d_in[13];
    const float* g2    = (const float*)d_in[14];
    const float* be2   = (const float*)d_in[15];
    const float* m2    = (const float*)d_in[16];
    const float* v2    = (const float*)d_in[17];
    const float* Wt    = (const float*)d_in[18];
    const float* bt    = (const float*)d_in[19];
    const float* Wc    = (const float*)d_in[20];
    const float* bc    = (const float*)d_in[21];
    float* out = (float*)d_out;

    // Workspace layout (16B-aligned chunks)
    char* p = (char*)d_ws;
    unsigned short* xbf  = (unsigned short*)p; p += (size_t)N_NODES * DIM * 2;  // 12.8 MB
    unsigned short* bufA = (unsigned short*)p; p += (size_t)N_NODES * DIM * 2;  // 12.8 MB
    unsigned short* bufB = (unsigned short*)p; p += (size_t)N_NODES * DIM * 2;  // 12.8 MB
    float* xs      = (float*)p; p += (size_t)BGRAPHS * DIM * 4;                 // 256 KB
    int*   deg     = (int*)p;   p += (size_t)(N_NODES + 16) * 4;
    int*   rowptr  = (int*)p;   p += (size_t)(N_NODES + 16) * 4;
    int*   cursor  = (int*)p;   p += (size_t)(N_NODES + 16) * 4;
    int*   bsum    = (int*)p;   p += 256 * 4;
    int*   csr_src = (int*)p;                                                   // 4.8 MB

    const int NB_N  = (N_NODES + 255) / 256;     // 391
    const int NB_E  = (N_EDGES + 255) / 256;     // 4688
    const int NB_SC = (N_NODES + 1023) / 1024;   // 98
    const int NB_C  = (N_NODES * DIM / 8 + 255) / 256;   // 3125

    zero_kernel<<<NB_N, 256, 0, stream>>>(deg, xs);
    convert_kernel<<<NB_C, 256, 0, stream>>>(x, xbf);
    hist_kernel<<<NB_E, 256, 0, stream>>>(ei, deg);
    scan1_kernel<<<NB_SC, 256, 0, stream>>>(deg, rowptr, bsum);
    scan2_kernel<<<1, 128, 0, stream>>>(bsum, NB_SC);
    scan3_kernel<<<NB_N, 256, 0, stream>>>(rowptr, bsum, cursor);
    fill_kernel<<<NB_E, 256, 0, stream>>>(ei, cursor, csr_src);

    // agg1: bufA = xbf + scatter(xbf)
    gather_kernel<<<(N_NODES + 31) / 32, 256, 0, stream>>>(xbf, rowptr, csr_src, bufA);
    // conv1 MLP (MFMA): bufB = h2 (bf16)
    mlp1_kernel<<<(N_NODES + 63) / 64, 256, 0, stream>>>(
        bufA, W1a, b1a, g1, be1, m1, v1, W1b, b1b, bufB);
    // agg2: bufA = h2 + scatter(h2)
    gather_kernel<<<(N_NODES + 31) / 32, 256, 0, stream>>>(bufB, rowptr, csr_src, bufA);
    // conv2 + pool (MFMA)
    mlp2_kernel<<<(N_NODES + 63) / 64, 256, 0, stream>>>(
        bufA, W2, b2, g2, be2, m2, v2, batch, xs);
    // head
    head_kernel<<<BGRAPHS, 64, 0, stream>>>(xs, topo, Wt, bt, Wc, bc, out);
}

// Round 4
// 246.256 us; speedup vs baseline: 9.1662x; 1.3599x over previous
//
#include <hip/hip_runtime.h>

// Problem constants (match reference)
#define N_NODES 100000
#define N_EDGES 1200000
#define DIM     64
#define BGRAPHS 1000
#define NCLASS  10
#define BN_EPS  1e-5f

// CSR-build partition constants
#define NBUCK   256            // coarse buckets
#define NPB     391            // nodes per bucket (256*391 = 100096 >= N)
#define MAGIC   10984572u      // ceil(2^32/391): bucket = umulhi(d, MAGIC)
#define CHUNK   8192           // edges per partition block
#define NBLK_P  147            // ceil(E / CHUNK)
#define SCAN_N  (NBUCK * NBLK_P)   // 37632
#define CAP     8192           // refine LDS staging capacity (>= max bucket edges)

typedef __attribute__((ext_vector_type(8))) short   bfx8;   // 8 bf16 MFMA A/B frag
typedef __attribute__((ext_vector_type(4))) float   f32x4;  // MFMA C/D frag
typedef __attribute__((ext_vector_type(8))) unsigned short u16x8;

__device__ __forceinline__ unsigned short f2bf(float f) {
    unsigned u = __builtin_bit_cast(unsigned, f);
    unsigned r = (u + 0x7FFFu + ((u >> 16) & 1u)) >> 16;   // RNE
    return (unsigned short)r;
}
__device__ __forceinline__ float bf2f(unsigned short h) {
    unsigned u = ((unsigned)h) << 16;
    return __builtin_bit_cast(float, u);
}

// ---------------------------------------------------------------------------
// fp32 -> bf16 convert (8 floats/thread) + zero xs
// ---------------------------------------------------------------------------
__global__ void convert_kernel(const float* __restrict__ x, unsigned short* __restrict__ xb,
                               float* __restrict__ xs) {
    int i = blockIdx.x * blockDim.x + threadIdx.x;
    const int n8 = N_NODES * DIM / 8;
    if (i < n8) {
        float4 a = ((const float4*)x)[i * 2];
        float4 b = ((const float4*)x)[i * 2 + 1];
        u16x8 o;
        o[0] = f2bf(a.x); o[1] = f2bf(a.y); o[2] = f2bf(a.z); o[3] = f2bf(a.w);
        o[4] = f2bf(b.x); o[5] = f2bf(b.y); o[6] = f2bf(b.z); o[7] = f2bf(b.w);
        ((u16x8*)xb)[i] = o;
    }
    if (i < BGRAPHS * DIM) xs[i] = 0.f;
}

// ---------------------------------------------------------------------------
// Phase A: per-(block,bucket) histogram via LDS; hist[bucket*NBLK_P + blk]
// ---------------------------------------------------------------------------
__global__ __launch_bounds__(256) void histA_kernel(const int* __restrict__ ei,
                                                    int* __restrict__ hist) {
    __shared__ int cnt[NBUCK];
    int t = threadIdx.x, blk = blockIdx.x;
    cnt[t] = 0;
    __syncthreads();
    int e0 = blk * CHUNK;
    for (int i = t; i < CHUNK; i += 256) {
        int e = e0 + i;
        if (e >= N_EDGES) break;
        unsigned d = (unsigned)ei[N_EDGES + e];
        int b = __umulhi(d, MAGIC);
        atomicAdd(&cnt[b], 1);
    }
    __syncthreads();
    hist[t * NBLK_P + blk] = cnt[t];
}

// ---------------------------------------------------------------------------
// Scan step 1: per-block (1024-elem) exclusive scan, block sums -> bsum
// ---------------------------------------------------------------------------
__global__ __launch_bounds__(256) void scan1_kernel(const int* __restrict__ in,
                                                    int* __restrict__ outp,
                                                    int* __restrict__ bsum, int n) {
    __shared__ int tmp[256];
    int t = threadIdx.x;
    int base = blockIdx.x * 1024;
    int v[4]; int s = 0;
    #pragma unroll
    for (int j = 0; j < 4; ++j) {
        int idx = base + t * 4 + j;
        v[j] = (idx < n) ? in[idx] : 0;
        s += v[j];
    }
    tmp[t] = s;
    __syncthreads();
    for (int off = 1; off < 256; off <<= 1) {
        int a = (t >= off) ? tmp[t - off] : 0;
        __syncthreads();
        tmp[t] += a;
        __syncthreads();
    }
    int excl = tmp[t] - s;
    if (t == 255) bsum[blockIdx.x] = tmp[255];
    int run = excl;
    #pragma unroll
    for (int j = 0; j < 4; ++j) {
        int idx = base + t * 4 + j;
        if (idx < n) outp[idx] = run;
        run += v[j];
    }
}

__global__ __launch_bounds__(128) void scan2_kernel(int* __restrict__ bsum, int nb) {
    __shared__ int tmp[128];
    int t = threadIdx.x;
    int v = (t < nb) ? bsum[t] : 0;
    tmp[t] = v;
    __syncthreads();
    for (int off = 1; off < 128; off <<= 1) {
        int a = (t >= off) ? tmp[t - off] : 0;
        __syncthreads();
        tmp[t] += a;
        __syncthreads();
    }
    if (t < nb) bsum[t] = tmp[t] - v;
}

__global__ void scan3_kernel(int* __restrict__ arr, const int* __restrict__ bsum, int n) {
    int i = blockIdx.x * blockDim.x + threadIdx.x;
    if (i < n) arr[i] += bsum[i >> 10];
}

// ---------------------------------------------------------------------------
// Phase C: partition edges into bucket regions (near-sequential per stream).
// Writes src (int) and dst_local (u16).
// ---------------------------------------------------------------------------
__global__ __launch_bounds__(256) void part_kernel(const int* __restrict__ ei,
                                                   const int* __restrict__ base,
                                                   int* __restrict__ srcbuf,
                                                   unsigned short* __restrict__ dstlbuf) {
    __shared__ int cur[NBUCK];
    int t = threadIdx.x, blk = blockIdx.x;
    cur[t] = base[t * NBLK_P + blk];
    __syncthreads();
    int e0 = blk * CHUNK;
    for (int i = t; i < CHUNK; i += 256) {
        int e = e0 + i;
        if (e >= N_EDGES) break;
        unsigned d = (unsigned)ei[N_EDGES + e];
        int s = ei[e];
        int b = __umulhi(d, MAGIC);
        int pos = atomicAdd(&cur[b], 1);
        srcbuf[pos] = s;
        dstlbuf[pos] = (unsigned short)(d - b * NPB);
    }
}

// ---------------------------------------------------------------------------
// Refine: one block per bucket; LDS counting sort by dst_local; coalesced
// csr_src write; emits rowptr from the local exclusive scan.
// ---------------------------------------------------------------------------
__global__ __launch_bounds__(256) void refine_kernel(const int* __restrict__ srcbuf,
                                                     const unsigned short* __restrict__ dstlbuf,
                                                     const int* __restrict__ base,
                                                     int* __restrict__ csr_src,
                                                     int* __restrict__ rowptr) {
    __shared__ int cnt[NPB + 1];
    __shared__ int cur[NPB + 1];
    __shared__ int tmp[256];
    __shared__ int outb[CAP];
    int t = threadIdx.x, b = blockIdx.x;
    int beg = base[b * NBLK_P];
    int end = (b == NBUCK - 1) ? N_EDGES : base[(b + 1) * NBLK_P];

    for (int i = t; i < NPB + 1; i += 256) cnt[i] = 0;
    __syncthreads();
    for (int i = beg + t; i < end; i += 256)
        atomicAdd(&cnt[dstlbuf[i]], 1);
    __syncthreads();

    // exclusive scan over NPB entries (2 elems/thread)
    int i0 = 2 * t, i1 = 2 * t + 1;
    int v0 = (i0 < NPB) ? cnt[i0] : 0;
    int v1 = (i1 < NPB) ? cnt[i1] : 0;
    int s = v0 + v1;
    tmp[t] = s;
    __syncthreads();
    for (int off = 1; off < 256; off <<= 1) {
        int a = (t >= off) ? tmp[t - off] : 0;
        __syncthreads();
        tmp[t] += a;
        __syncthreads();
    }
    int excl = tmp[t] - s;
    if (i0 < NPB) cur[i0] = excl;
    if (i1 < NPB) cur[i1] = excl + v0;
    {
        int g0 = b * NPB + i0;
        if (i0 < NPB && g0 < N_NODES) rowptr[g0] = beg + excl;
        int g1 = b * NPB + i1;
        if (i1 < NPB && g1 < N_NODES) rowptr[g1] = beg + excl + v0;
    }
    if (b == NBUCK - 1 && t == 0) rowptr[N_NODES] = N_EDGES;
    __syncthreads();

    for (int i = beg + t; i < end; i += 256) {
        int dl = dstlbuf[i];
        int pos = atomicAdd(&cur[dl], 1);
        if (pos < CAP) outb[pos] = srcbuf[i];
    }
    __syncthreads();

    int nb = end - beg; if (nb > CAP) nb = CAP;
    for (int i = t; i < nb; i += 256) csr_src[beg + i] = outb[i];
}

// ---------------------------------------------------------------------------
// bf16 gather aggregation: out[i] = feat[i] + sum_{s in nbrs(i)} feat[s]
// 8 lanes per node (16B/lane), 32 nodes per 256-thread block.
// ---------------------------------------------------------------------------
__global__ __launch_bounds__(256) void gather_kernel(const unsigned short* __restrict__ feat,
                                                     const int* __restrict__ rowptr,
                                                     const int* __restrict__ csr_src,
                                                     unsigned short* __restrict__ out) {
    int t = threadIdx.x;
    int node = blockIdx.x * 32 + (t >> 3);
    int q = t & 7;
    if (node >= N_NODES) return;
    const u16x8* f8 = (const u16x8*)feat;
    u16x8 sv = f8[(long long)node * 8 + q];
    float acc[8];
    #pragma unroll
    for (int j = 0; j < 8; ++j) acc[j] = bf2f(sv[j]);
    int beg = rowptr[node], end = rowptr[node + 1];
    int k = beg;
    int sn = (k < end) ? csr_src[k] : 0;
    while (k < end) {
        int sc = sn;
        ++k;
        if (k < end) sn = csr_src[k];
        u16x8 v = f8[(long long)sc * 8 + q];
        #pragma unroll
        for (int j = 0; j < 8; ++j) acc[j] += bf2f(v[j]);
    }
    u16x8 o;
    #pragma unroll
    for (int j = 0; j < 8; ++j) o[j] = f2bf(acc[j]);
    ((u16x8*)out)[(long long)node * 8 + q] = o;
}

// ---------------------------------------------------------------------------
// B-fragment loader: element j = W[(kt*32 + q*8 + j)][col]  (fp32 W -> bf16)
// ---------------------------------------------------------------------------
__device__ __forceinline__ bfx8 load_wfrag(const float* __restrict__ W, int kt, int q, int col) {
    bfx8 f;
    #pragma unroll
    for (int j = 0; j < 8; ++j)
        f[j] = (short)f2bf(W[(kt * 32 + q * 8 + j) * 64 + col]);
    return f;
}

// ---------------------------------------------------------------------------
// MFMA conv1 MLP: h2 = relu(relu(bn1(h0 @ W1a + b1a)) @ W1b + b1b)
// ---------------------------------------------------------------------------
__global__ __launch_bounds__(256) void mlp1_kernel(
    const unsigned short* __restrict__ h0,
    const float* __restrict__ W1a, const float* __restrict__ b1a,
    const float* __restrict__ g1,  const float* __restrict__ be1,
    const float* __restrict__ m1,  const float* __restrict__ v1,
    const float* __restrict__ W1b, const float* __restrict__ b1b,
    unsigned short* __restrict__ h2) {
    __shared__ unsigned short h1t[4][16 * 72];
    __shared__ unsigned short outt[4][16 * 64];

    int t = threadIdx.x;
    int w = t >> 6, lane = t & 63;
    int m = lane & 15, q = lane >> 4;
    int row0 = blockIdx.x * 64 + w * 16;

    bfx8 wa[4][2], wb[4][2];
    #pragma unroll
    for (int nt = 0; nt < 4; ++nt) {
        #pragma unroll
        for (int kt = 0; kt < 2; ++kt) {
            wa[nt][kt] = load_wfrag(W1a, kt, q, nt * 16 + m);
            wb[nt][kt] = load_wfrag(W1b, kt, q, nt * 16 + m);
        }
    }
    float A1[4], B1[4], B2c[4];
    #pragma unroll
    for (int nt = 0; nt < 4; ++nt) {
        int c = nt * 16 + m;
        float s = g1[c] * rsqrtf(v1[c] + BN_EPS);
        A1[nt] = s;
        B1[nt] = b1a[c] * s + (be1[c] - m1[c] * s);
        B2c[nt] = b1b[c];
    }

    int rowA = row0 + m;
    if (rowA > N_NODES - 1) rowA = N_NODES - 1;
    const bfx8* ap = (const bfx8*)(h0 + (long long)rowA * 64);
    bfx8 a0 = ap[q];
    bfx8 a1 = ap[4 + q];
    f32x4 acc[4];
    #pragma unroll
    for (int nt = 0; nt < 4; ++nt) {
        acc[nt] = (f32x4){0.f, 0.f, 0.f, 0.f};
        acc[nt] = __builtin_amdgcn_mfma_f32_16x16x32_bf16(a0, wa[nt][0], acc[nt], 0, 0, 0);
        acc[nt] = __builtin_amdgcn_mfma_f32_16x16x32_bf16(a1, wa[nt][1], acc[nt], 0, 0, 0);
    }
    #pragma unroll
    for (int nt = 0; nt < 4; ++nt)
        #pragma unroll
        for (int r = 0; r < 4; ++r) {
            float v = fmaxf(acc[nt][r] * A1[nt] + B1[nt], 0.f);
            h1t[w][(q * 4 + r) * 72 + nt * 16 + m] = f2bf(v);
        }
    __syncthreads();

    const bfx8* hp = (const bfx8*)&h1t[w][m * 72];
    bfx8 c0 = hp[q];
    bfx8 c1 = hp[4 + q];
    f32x4 acc2[4];
    #pragma unroll
    for (int nt = 0; nt < 4; ++nt) {
        acc2[nt] = (f32x4){0.f, 0.f, 0.f, 0.f};
        acc2[nt] = __builtin_amdgcn_mfma_f32_16x16x32_bf16(c0, wb[nt][0], acc2[nt], 0, 0, 0);
        acc2[nt] = __builtin_amdgcn_mfma_f32_16x16x32_bf16(c1, wb[nt][1], acc2[nt], 0, 0, 0);
    }
    #pragma unroll
    for (int nt = 0; nt < 4; ++nt)
        #pragma unroll
        for (int r = 0; r < 4; ++r) {
            float v = fmaxf(acc2[nt][r] + B2c[nt], 0.f);
            outt[w][(q * 4 + r) * 64 + nt * 16 + m] = f2bf(v);
        }
    __syncthreads();

    #pragma unroll
    for (int i = lane; i < 128; i += 64) {
        int rr = i >> 3, cc = i & 7;
        int rg = row0 + rr;
        if (rg < N_NODES)
            ((float4*)h2)[(long long)rg * 8 + cc] = *(const float4*)&outt[w][rr * 64 + cc * 8];
    }
}

// ---------------------------------------------------------------------------
// MFMA conv2 + pool: h4 = relu(bn2(h3 @ W2 + b2)); xs[batch[row]] += h4
// ---------------------------------------------------------------------------
__global__ __launch_bounds__(256) void mlp2_kernel(
    const unsigned short* __restrict__ h3,
    const float* __restrict__ W2, const float* __restrict__ b2,
    const float* __restrict__ g2, const float* __restrict__ be2,
    const float* __restrict__ m2, const float* __restrict__ v2,
    const int* __restrict__ batch,
    float* __restrict__ xs) {
    __shared__ float pool[64 * 64];
    __shared__ int bts[64];

    int t = threadIdx.x;
    int w = t >> 6, lane = t & 63;
    int m = lane & 15, q = lane >> 4;
    int row0b = blockIdx.x * 64;
    int row0 = row0b + w * 16;

    bfx8 wf[4][2];
    #pragma unroll
    for (int nt = 0; nt < 4; ++nt)
        #pragma unroll
        for (int kt = 0; kt < 2; ++kt)
            wf[nt][kt] = load_wfrag(W2, kt, q, nt * 16 + m);
    float A[4], Bc[4];
    #pragma unroll
    for (int nt = 0; nt < 4; ++nt) {
        int c = nt * 16 + m;
        float s = g2[c] * rsqrtf(v2[c] + BN_EPS);
        A[nt] = s;
        Bc[nt] = b2[c] * s + (be2[c] - m2[c] * s);
    }
    if (t < 64) {
        int rg = row0b + t;
        bts[t] = (rg < N_NODES) ? batch[rg] : -1;
    }

    int rowA = row0 + m;
    if (rowA > N_NODES - 1) rowA = N_NODES - 1;
    const bfx8* ap = (const bfx8*)(h3 + (long long)rowA * 64);
    bfx8 a0 = ap[q];
    bfx8 a1 = ap[4 + q];
    f32x4 acc[4];
    #pragma unroll
    for (int nt = 0; nt < 4; ++nt) {
        acc[nt] = (f32x4){0.f, 0.f, 0.f, 0.f};
        acc[nt] = __builtin_amdgcn_mfma_f32_16x16x32_bf16(a0, wf[nt][0], acc[nt], 0, 0, 0);
        acc[nt] = __builtin_amdgcn_mfma_f32_16x16x32_bf16(a1, wf[nt][1], acc[nt], 0, 0, 0);
    }
    #pragma unroll
    for (int nt = 0; nt < 4; ++nt)
        #pragma unroll
        for (int r = 0; r < 4; ++r) {
            float v = fmaxf(acc[nt][r] * A[nt] + Bc[nt], 0.f);
            pool[(w * 16 + q * 4 + r) * 64 + nt * 16 + m] = v;
        }
    __syncthreads();

    int col = t & 63;
    int r0 = (t >> 6) * 16;
    int cb = bts[r0];
    float cur = 0.f;
    #pragma unroll
    for (int r = 0; r < 16; ++r) {
        int b = bts[r0 + r];
        if (b != cb) {
            if (cb >= 0) unsafeAtomicAdd(&xs[cb * 64 + col], cur);
            cb = b;
            cur = 0.f;
        }
        cur += pool[(r0 + r) * 64 + col];
    }
    if (cb >= 0) unsafeAtomicAdd(&xs[cb * 64 + col], cur);
}

// ---------------------------------------------------------------------------
// Head: x_topo = relu(topo @ Wt + bt); out = [x_struct, x_topo] @ Wc + bc
// ---------------------------------------------------------------------------
__global__ __launch_bounds__(64) void head_kernel(
    const float* __restrict__ xs, const float* __restrict__ topo,
    const float* __restrict__ Wt, const float* __restrict__ bt,
    const float* __restrict__ Wc, const float* __restrict__ bc,
    float* __restrict__ out) {
    __shared__ float trow[64];
    __shared__ float comb[128];
    int b = blockIdx.x;
    int h = threadIdx.x;
    trow[h] = topo[b * 64 + h];
    __syncthreads();
    float acc = bt[h];
    #pragma unroll
    for (int k = 0; k < 64; ++k) acc += trow[k] * Wt[k * 64 + h];
    comb[h] = xs[b * 64 + h];
    comb[64 + h] = fmaxf(acc, 0.f);
    __syncthreads();
    if (h < NCLASS) {
        float o = bc[h];
        #pragma unroll
        for (int k = 0; k < 128; ++k) o += comb[k] * Wc[k * NCLASS + h];
        out[b * NCLASS + h] = o;
    }
}

// ---------------------------------------------------------------------------
extern "C" void kernel_launch(void* const* d_in, const int* in_sizes, int n_in,
                              void* d_out, int out_size, void* d_ws, size_t ws_size,
                              hipStream_t stream) {
    const float* x     = (const float*)d_in[0];
    const int*   ei    = (const int*)d_in[1];
    const int*   batch = (const int*)d_in[2];
    const float* topo  = (const float*)d_in[3];
    const float* W1a   = (const float*)d_in[4];
    const float* b1a   = (const float*)d_in[5];
    const float* g1    = (const float*)d_in[6];
    const float* be1   = (const float*)d_in[7];
    const float* m1    = (const float*)d_in[8];
    const float* v1    = (const float*)d_in[9];
    const float* W1b   = (const float*)d_in[10];
    const float* b1b   = (const float*)d_in[11];
    const float* W2    = (const float*)d_in[12];
    const float* b2    = (const float*)d_in[13];
    const float* g2    = (const float*)d_in[14];
    const float* be2   = (const float*)d_in[15];
    const float* m2    = (const float*)d_in[16];
    const float* v2    = (const float*)d_in[17];
    const float* Wt    = (const float*)d_in[18];
    const float* bt    = (const float*)d_in[19];
    const float* Wc    = (const float*)d_in[20];
    const float* bc    = (const float*)d_in[21];
    float* out = (float*)d_out;

    // Workspace layout (16B-aligned chunks)
    char* p = (char*)d_ws;
    unsigned short* xbf  = (unsigned short*)p; p += (size_t)N_NODES * DIM * 2;  // 12.8 MB
    unsigned short* bufA = (unsigned short*)p; p += (size_t)N_NODES * DIM * 2;  // 12.8 MB
    unsigned short* bufB = (unsigned short*)p; p += (size_t)N_NODES * DIM * 2;  // 12.8 MB
    float* xs      = (float*)p; p += (size_t)BGRAPHS * DIM * 4;                 // 256 KB
    int*   rowptr  = (int*)p;   p += (size_t)(N_NODES + 16) * 4;                // 400 KB
    int*   histc   = (int*)p;   p += (size_t)SCAN_N * 4;                        // 150 KB
    int*   base    = (int*)p;   p += (size_t)SCAN_N * 4;                        // 150 KB
    int*   bsum    = (int*)p;   p += 256 * 4;
    int*   srcbuf  = (int*)p;   p += (size_t)N_EDGES * 4;                       // 4.8 MB
    unsigned short* dstlbuf = (unsigned short*)p; p += (size_t)N_EDGES * 2;     // 2.4 MB
    int*   csr_src = (int*)p;                                                   // 4.8 MB

    const int NB_C  = (N_NODES * DIM / 8 + 255) / 256;   // 3125
    const int NB_S1 = (SCAN_N + 1023) / 1024;            // 37
    const int NB_S3 = (SCAN_N + 255) / 256;              // 147

    convert_kernel<<<NB_C, 256, 0, stream>>>(x, xbf, xs);
    histA_kernel<<<NBLK_P, 256, 0, stream>>>(ei, histc);
    scan1_kernel<<<NB_S1, 256, 0, stream>>>(histc, base, bsum, SCAN_N);
    scan2_kernel<<<1, 128, 0, stream>>>(bsum, NB_S1);
    scan3_kernel<<<NB_S3, 256, 0, stream>>>(base, bsum, SCAN_N);
    part_kernel<<<NBLK_P, 256, 0, stream>>>(ei, base, srcbuf, dstlbuf);
    refine_kernel<<<NBUCK, 256, 0, stream>>>(srcbuf, dstlbuf, base, csr_src, rowptr);

    // agg1: bufA = xbf + scatter(xbf)
    gather_kernel<<<(N_NODES + 31) / 32, 256, 0, stream>>>(xbf, rowptr, csr_src, bufA);
    // conv1 MLP (MFMA): bufB = h2 (bf16)
    mlp1_kernel<<<(N_NODES + 63) / 64, 256, 0, stream>>>(
        bufA, W1a, b1a, g1, be1, m1, v1, W1b, b1b, bufB);
    // agg2: bufA = h2 + scatter(h2)
    gather_kernel<<<(N_NODES + 31) / 32, 256, 0, stream>>>(bufB, rowptr, csr_src, bufA);
    // conv2 + pool (MFMA)
    mlp2_kernel<<<(N_NODES + 63) / 64, 256, 0, stream>>>(
        bufA, W2, b2, g2, be2, m2, v2, batch, xs);
    // head
    head_kernel<<<BGRAPHS, 64, 0, stream>>>(xs, topo, Wt, bt, Wc, bc, out);
}